// Round 2
// baseline (1398.295 us; speedup 1.0000x reference)
//
#include <hip/hip_runtime.h>
#include <hip/hip_bf16.h>

typedef unsigned short u16;

#define LEAKY 0.2f

__device__ __forceinline__ float bu2f(u16 v) {
    return __uint_as_float(((unsigned)v) << 16);
}
__device__ __forceinline__ u16 f2bu(float f) {
    unsigned u = __float_as_uint(f);
    unsigned r = (u + 0x7FFFu + ((u >> 16) & 1u)) >> 16;
    return (u16)r;
}
__device__ __forceinline__ unsigned fmapu(float f) {
    unsigned u = __float_as_uint(f);
    return (u & 0x80000000u) ? ~u : (u | 0x80000000u);
}
__device__ __forceinline__ float funmapu(unsigned u) {
    return __uint_as_float((u & 0x80000000u) ? (u & 0x7FFFFFFFu) : ~u);
}

// ---------------- CSR build ----------------

__global__ void k_init(int* deg, unsigned* gmaxb, float* sumexp, int N) {
    int i = blockIdx.x * blockDim.x + threadIdx.x;
    if (i < N) deg[i] = 1;  // self loop
    if (i == 0) { *gmaxb = 0u; *sumexp = 0.f; }
}

__global__ void k_count(const int* __restrict__ dst, int* __restrict__ deg, int E) {
    int i = blockIdx.x * blockDim.x + threadIdx.x;
    if (i < E) atomicAdd(&deg[dst[i]], 1);
}

__global__ void k_scan(const int* __restrict__ deg, int* __restrict__ rowst, int N) {
    // single block, 1024 threads
    __shared__ int part[1024];
    int t = threadIdx.x;
    int chunk = (N + 1023) / 1024;
    int lo = t * chunk;
    int hi = min(lo + chunk, N);
    int s = 0;
    for (int i = lo; i < hi; ++i) s += deg[i];
    part[t] = s;
    __syncthreads();
    if (t == 0) {
        int run = 0;
        for (int i = 0; i < 1024; ++i) { int v = part[i]; part[i] = run; run += v; }
    }
    __syncthreads();
    int run = part[t];
    for (int i = lo; i < hi; ++i) { rowst[i] = run; run += deg[i]; }
    if (hi == N && lo < N) rowst[N] = run;
}

__global__ void k_selfloop(const int* __restrict__ rowst, int* __restrict__ cursor,
                           int* __restrict__ adj, int N) {
    int i = blockIdx.x * blockDim.x + threadIdx.x;
    if (i < N) {
        int p = rowst[i];
        adj[p] = i;          // self loop first
        cursor[i] = p + 1;
    }
}

__global__ void k_scatter(const int* __restrict__ src, const int* __restrict__ dst,
                          int* __restrict__ cursor, int* __restrict__ adj, int E) {
    int i = blockIdx.x * blockDim.x + threadIdx.x;
    if (i < E) {
        int pos = atomicAdd(&cursor[dst[i]], 1);
        adj[pos] = src[i];
    }
}

// ---------------- GEMM (N x 128) @ (128 x 128) + attention-coef epilogue ----------------

template <typename T>
__device__ __forceinline__ float ldv(const T* p, size_t i);
template <>
__device__ __forceinline__ float ldv<float>(const float* p, size_t i) { return p[i]; }
template <>
__device__ __forceinline__ float ldv<u16>(const u16* p, size_t i) { return bu2f(p[i]); }

template <int H, typename TIN>
__global__ __launch_bounds__(128) void k_gemm_att(
    const TIN* __restrict__ in, const float* __restrict__ W,
    const float* __restrict__ att_s, const float* __restrict__ att_d,
    u16* __restrict__ out, float* __restrict__ a_src, float* __restrict__ a_dst, int N) {
    __shared__ float Wl[128 * 128];
    __shared__ float xr[128];
    __shared__ float r2s[2], r2d[2];
    int c = threadIdx.x;
    for (int i = 0; i < 128; ++i) Wl[i * 128 + c] = W[i * 128 + c];
    float atts = att_s[c];
    float attd = att_d[c];
    int r0 = blockIdx.x * 32;
    int rend = min(r0 + 32, N);
    for (int r = r0; r < rend; ++r) {
        __syncthreads();
        xr[c] = ldv(in, (size_t)r * 128 + c);
        __syncthreads();
        float acc = 0.f;
#pragma unroll 8
        for (int k = 0; k < 128; ++k) acc += xr[k] * Wl[k * 128 + c];
        out[(size_t)r * 128 + c] = f2bu(acc);
        float ps = acc * atts;
        float pd = acc * attd;
#pragma unroll
        for (int o = 32; o > 0; o >>= 1) {
            ps += __shfl_down(ps, o);
            pd += __shfl_down(pd, o);
        }
        if (H == 2) {
            if ((c & 63) == 0) {
                int h = c >> 6;
                a_src[(size_t)r * 2 + h] = ps;
                a_dst[(size_t)r * 2 + h] = pd;
            }
        } else {
            if ((c & 63) == 0) { r2s[c >> 6] = ps; r2d[c >> 6] = pd; }
            __syncthreads();
            if (c == 0) {
                a_src[r] = r2s[0] + r2s[1];
                a_dst[r] = r2d[0] + r2d[1];
            }
        }
    }
}

// ---------------- per-node segment softmax + aggregation (online) ----------------

template <int H, typename TOUT>
__global__ __launch_bounds__(128) void k_agg(
    const int* __restrict__ rowst, const int* __restrict__ adj,
    const float* __restrict__ a_src, const float* __restrict__ a_dst,
    const u16* __restrict__ h_in, const float* __restrict__ bias,
    TOUT* __restrict__ out, int N) {
    int n = blockIdx.x;
    if (n >= N) return;
    const int Ch = 128 / H;
    int c = threadIdx.x;
    int h = c / Ch;
    __shared__ float sm_m[H], sm_s[H], sscale[H];
    __shared__ int srcs[64];
    __shared__ float ev[H][64], pv[H][64];
    if (c < H) { sm_m[c] = -1e30f; sm_s[c] = 0.f; }
    float acc = 0.f;
    int rs = rowst[n], re = rowst[n + 1];
    __syncthreads();
    for (int base = rs; base < re; base += 64) {
        int cnt = min(64, re - base);
        if (c < cnt) {
            int s = adj[base + c];
            srcs[c] = s;
#pragma unroll
            for (int hh = 0; hh < H; ++hh) {
                float xv = a_src[(size_t)s * H + hh] + a_dst[(size_t)n * H + hh];
                ev[hh][c] = (xv > 0.f) ? xv : LEAKY * xv;
            }
        }
        __syncthreads();
        if (c < H) {
            float mx = sm_m[c];
            for (int e = 0; e < cnt; ++e) mx = fmaxf(mx, ev[c][e]);
            float sc = __expf(sm_m[c] - mx);
            float ss = sm_s[c] * sc;
            for (int e = 0; e < cnt; ++e) {
                float pe = __expf(ev[c][e] - mx);
                pv[c][e] = pe;
                ss += pe;
            }
            sm_m[c] = mx; sm_s[c] = ss; sscale[c] = sc;
        }
        __syncthreads();
        acc *= sscale[h];
        for (int e = 0; e < cnt; ++e) {
            acc += pv[h][e] * bu2f(h_in[(size_t)srcs[e] * 128 + c]);
        }
        __syncthreads();
    }
    float val = acc / (sm_s[h] + 1e-16f) + bias[c];
    if constexpr (sizeof(TOUT) == 2) {
        out[(size_t)n * 128 + c] = (TOUT)f2bu(val);
    } else {
        out[(size_t)n * 128 + c] = (TOUT)val;
    }
}

// ---------------- score head ----------------

__global__ void k_cvec(const float* __restrict__ q, const float* __restrict__ Wq1,
                       const float* __restrict__ bq1, float* __restrict__ cvec) {
    int j = threadIdx.x;  // 128 threads
    float acc = bq1[j];
    for (int k = 0; k < 384; ++k) acc += q[k] * Wq1[(size_t)(128 + k) * 128 + j];
    cvec[j] = acc;
}

__global__ __launch_bounds__(128) void k_score(
    const float* __restrict__ h2, const float* __restrict__ Wq1, const float* __restrict__ Wq2,
    const float* __restrict__ bq2, const float* __restrict__ cvec,
    float* __restrict__ scores, unsigned* __restrict__ gmaxb, int N) {
    int n = blockIdx.x;
    if (n >= N) return;
    __shared__ float hr[128];
    __shared__ float w2r[2];
    int c = threadIdx.x;
    hr[c] = h2[(size_t)n * 128 + c];
    __syncthreads();
    float acc = cvec[c];
#pragma unroll 8
    for (int k = 0; k < 128; ++k) acc += hr[k] * Wq1[(size_t)k * 128 + c];
    float t = fmaxf(acc, 0.f) * Wq2[c];
#pragma unroll
    for (int o = 32; o > 0; o >>= 1) t += __shfl_down(t, o);
    if ((c & 63) == 0) w2r[c >> 6] = t;
    __syncthreads();
    if (c == 0) {
        float s = w2r[0] + w2r[1] + bq2[0];
        scores[n] = s;
        atomicMax(gmaxb, fmapu(s));
    }
}

__global__ void k_sumexp(float* __restrict__ scores, const unsigned* __restrict__ gmaxb,
                         float* __restrict__ sumexp, int N) {
    int i = blockIdx.x * blockDim.x + threadIdx.x;
    float gmax = funmapu(*gmaxb);
    float p = 0.f;
    if (i < N) {
        p = __expf(scores[i] - gmax);
        scores[i] = p;
    }
#pragma unroll
    for (int o = 32; o > 0; o >>= 1) p += __shfl_down(p, o);
    __shared__ float ws_[4];
    if ((threadIdx.x & 63) == 0) ws_[threadIdx.x >> 6] = p;
    __syncthreads();
    if (threadIdx.x == 0) atomicAdd(sumexp, ws_[0] + ws_[1] + ws_[2] + ws_[3]);
}

__global__ void k_final(const float* __restrict__ scores, const float* __restrict__ sumexp,
                        float* __restrict__ out_s, int N) {
    int i = blockIdx.x * blockDim.x + threadIdx.x;
    if (i < N) out_s[i] = scores[i] / *sumexp;
}

// ---------------- launch ----------------

extern "C" void kernel_launch(void* const* d_in, const int* in_sizes, int n_in,
                              void* d_out, int out_size, void* d_ws, size_t ws_size,
                              hipStream_t stream) {
    const float* x   = (const float*)d_in[0];
    const int*   ei  = (const int*)d_in[1];
    const float* q   = (const float*)d_in[3];
    const float* W1  = (const float*)d_in[4];
    const float* as1 = (const float*)d_in[5];
    const float* ad1 = (const float*)d_in[6];
    const float* b1  = (const float*)d_in[7];
    const float* W2  = (const float*)d_in[8];
    const float* as2 = (const float*)d_in[9];
    const float* ad2 = (const float*)d_in[10];
    const float* b2  = (const float*)d_in[11];
    const float* Wq1 = (const float*)d_in[12];
    const float* bq1 = (const float*)d_in[13];
    const float* Wq2 = (const float*)d_in[14];
    const float* bq2 = (const float*)d_in[15];

    const int N = in_sizes[0] / 128;
    const int E = in_sizes[1] / 2;
    const int ET = E + N;
    const int* esrc = ei;
    const int* edst = ei + E;

    char* p = (char*)d_ws;
    auto alloc = [&](size_t bytes) -> char* {
        char* r = p;
        p += (bytes + 255) & ~(size_t)255;
        return r;
    };
    u16*   hbufA  = (u16*)alloc((size_t)N * 128 * sizeof(u16));  // gemm outputs (bf16)
    u16*   hbufB  = (u16*)alloc((size_t)N * 128 * sizeof(u16));  // layer-1 result (bf16)
    float* asrc1  = (float*)alloc((size_t)N * 2 * sizeof(float));
    float* adst1  = (float*)alloc((size_t)N * 2 * sizeof(float));
    float* asrc2  = (float*)alloc((size_t)N * sizeof(float));
    float* adst2  = (float*)alloc((size_t)N * sizeof(float));
    int*   deg    = (int*)alloc((size_t)N * sizeof(int));
    int*   rowst  = (int*)alloc((size_t)(N + 1) * sizeof(int));
    int*   cursor = (int*)alloc((size_t)N * sizeof(int));
    int*   adjl   = (int*)alloc((size_t)ET * sizeof(int));
    float* scores = (float*)alloc((size_t)N * sizeof(float));
    float* cvec   = (float*)alloc(128 * sizeof(float));
    unsigned* gmaxb = (unsigned*)alloc(256);
    float* sumexp   = (float*)alloc(256);

    float* out_h = (float*)d_out;             // [N*128]
    float* out_s = out_h + (size_t)N * 128;   // [N]

    const int tb = 256;
    k_init<<<(N + tb - 1) / tb, tb, 0, stream>>>(deg, gmaxb, sumexp, N);
    k_count<<<(E + tb - 1) / tb, tb, 0, stream>>>(edst, deg, E);
    k_scan<<<1, 1024, 0, stream>>>(deg, rowst, N);
    k_selfloop<<<(N + tb - 1) / tb, tb, 0, stream>>>(rowst, cursor, adjl, N);
    k_scatter<<<(E + tb - 1) / tb, tb, 0, stream>>>(esrc, edst, cursor, adjl, E);

    // layer 1: heads=2  (x f32 -> h1 bf16)
    k_gemm_att<2, float><<<(N + 31) / 32, 128, 0, stream>>>(x, W1, as1, ad1, hbufA, asrc1, adst1, N);
    k_agg<2, u16><<<N, 128, 0, stream>>>(rowst, adjl, asrc1, adst1, hbufA, b1, hbufB, N);

    // layer 2: heads=1  (h1 bf16 -> h2 f32 into d_out)
    k_gemm_att<1, u16><<<(N + 31) / 32, 128, 0, stream>>>(hbufB, W2, as2, ad2, hbufA, asrc2, adst2, N);
    k_agg<1, float><<<N, 128, 0, stream>>>(rowst, adjl, asrc2, adst2, hbufA, b2, out_h, N);

    // score head
    k_cvec<<<1, 128, 0, stream>>>(q, Wq1, bq1, cvec);
    k_score<<<N, 128, 0, stream>>>(out_h, Wq1, Wq2, bq2, cvec, scores, gmaxb, N);
    k_sumexp<<<(N + tb - 1) / tb, tb, 0, stream>>>(scores, gmaxb, sumexp, N);
    k_final<<<(N + tb - 1) / tb, tb, 0, stream>>>(scores, sumexp, out_s, N);
}